// Round 5
// baseline (175.544 us; speedup 1.0000x reference)
//
#include <hip/hip_runtime.h>
#include <hip/hip_bf16.h>
#include <math.h>

#define EMBED 768
#define NTOK  4096
#define NB    4
#define ROWS  16384          // 4 * 4096
#define CN    192            // Q(64)|K(64)|V(64)

typedef __attribute__((ext_vector_type(8))) short bf16x8;       // 8 bf16 = 4 VGPR
typedef __attribute__((ext_vector_type(4))) float f32x4;        // MFMA acc
typedef __attribute__((ext_vector_type(4))) unsigned int u32x4; // 4 dwords

// Split fp32 -> h + l bf16 via packed RNE converts (~3 VALU/elem).
// f = h + l + eps, |eps| ~ 2^-18 |f|  (f - h is exact in fp32).
__device__ inline void split8(const float4& a0, const float4& a1,
                              bf16x8& h, bf16x8& l) {
  const float f[8] = {a0.x, a0.y, a0.z, a0.w, a1.x, a1.y, a1.z, a1.w};
  u32x4 hw, lw;
#pragma unroll
  for (int j = 0; j < 4; ++j) {
    float2 p = make_float2(f[2 * j], f[2 * j + 1]);
    __hip_bfloat162 hb = __float22bfloat162_rn(p);
    float2 hf = __bfloat1622float2(hb);
    __hip_bfloat162 lb =
        __float22bfloat162_rn(make_float2(p.x - hf.x, p.y - hf.y));
    union { __hip_bfloat162 b; unsigned u; } cu, cl;
    cu.b = hb; cl.b = lb;
    hw[j] = cu.u; lw[j] = cl.u;
  }
  h = __builtin_bit_cast(bf16x8, hw);
  l = __builtin_bit_cast(bf16x8, lw);
}

__device__ inline void split1(float f, unsigned short& h, unsigned short& l) {
  __hip_bfloat16 hb = __float2bfloat16(f);
  float hf = __bfloat162float(hb);
  __hip_bfloat16 lb = __float2bfloat16(f - hf);
  union { __hip_bfloat16 b; unsigned short u; } a, b2;
  a.b = hb; b2.b = lb;
  h = a.u; l = b2.u;
}

// ---------------------------------------------------------------------------
// W prep via LDS transpose: Wt[plane][n][k] bf16 (plane 0=high, 1=low).
// Grid 36 blocks: (k-tile 0..11) x (matrix 0..2). Reads coalesced (256B rows),
// writes in 128B contiguous chunks. Block 0 also zeroes Vsum (replaces memset).
// ---------------------------------------------------------------------------
__global__ __launch_bounds__(256) void wprep(const float* __restrict__ Wq,
                                             const float* __restrict__ Wk,
                                             const float* __restrict__ Wv,
                                             unsigned short* __restrict__ Wt,
                                             float* __restrict__ Vsum) {
  __shared__ float ld[64][65];
  const int t   = threadIdx.x;
  const int kt  = blockIdx.x / 3;     // k-tile: rows [kt*64, kt*64+64)
  const int mtx = blockIdx.x % 3;     // 0=Q, 1=K, 2=V
  const float* src = (mtx == 0) ? Wq : (mtx == 1) ? Wk : Wv;

  if (blockIdx.x == 0) Vsum[t] = 0.f;   // NB*64 == 256

  // read phase: 64 k-rows x 64 cols, coalesced
  const int col = t & 63;
  const int kr0 = (t >> 6) * 16;
#pragma unroll
  for (int r = 0; r < 16; ++r)
    ld[kr0 + r][col] = src[(size_t)(kt * 64 + kr0 + r) * 64 + col];
  __syncthreads();

  // write phase: thread owns (n = mtx*64 + t>>2, k chunk = (t&3)*16 + [0,16))
  const int nl = t >> 2;
  const int kc = (t & 3) * 16;
  unsigned short hb[16], lb2[16];
#pragma unroll
  for (int r = 0; r < 16; ++r) split1(ld[kc + r][nl], hb[r], lb2[r]);

  const int n = mtx * 64 + nl;
  unsigned short* dh = Wt + (size_t)n * EMBED + kt * 64 + kc;
  unsigned short* dl = Wt + (size_t)(CN + n) * EMBED + kt * 64 + kc;
  *(u32x4*)(dh)     = *(u32x4*)(hb);
  *(u32x4*)(dh + 8) = *(u32x4*)(hb + 8);
  *(u32x4*)(dl)     = *(u32x4*)(lb2);
  *(u32x4*)(dl + 8) = *(u32x4*)(lb2 + 8);
}

// ---------------------------------------------------------------------------
// MFMA GEMM: C[16384][192] = x @ W + bias, split-bf16, flat register pipeline
// (no LDS, no barriers — the only structure the allocator handles well here).
// Block = 256 thr = 4 waves, one m-tile of 16 rows. Wave wn covers n-tiles
// {wn, wn+4, wn+8}: statically 2 Q/K tiles (3-pass) + 1 V tile (1-pass).
// Grid 1024 blocks -> 4096 waves = 4 waves/SIMD. B frags from L2 (Wt 576KB).
// Epilogue: bias, fused Vsum row-reduction (atomics), store.
// ---------------------------------------------------------------------------
__global__ __launch_bounds__(256) void qkv_mfma(
    const float* __restrict__ x, const unsigned short* __restrict__ Wtu,
    const float* __restrict__ bq, const float* __restrict__ bk,
    const float* __restrict__ bv, float* __restrict__ C,
    float* __restrict__ Vsum) {
  const int lane = threadIdx.x & 63;
  const int wn   = threadIdx.x >> 6;   // 0..3
  const int ml   = lane & 15;
  const int qd   = lane >> 4;          // quad: k = qd*8 + j
  const int r0   = blockIdx.x * 16;
  const int batch = blockIdx.x >> 8;   // 256 blocks per batch

  const bf16x8* wt = (const bf16x8*)Wtu;

  // tiles: j=0,1 are Q/K (full 3-pass), j=2 is V (1-pass). n = (wn+4j)*16+ml.
  int nn[3], bh_base[3], bl_base[2];
#pragma unroll
  for (int j = 0; j < 3; ++j) {
    nn[j] = (wn + 4 * j) * 16 + ml;
    bh_base[j] = nn[j] * 96 + qd;
    if (j < 2) bl_base[j] = (CN + nn[j]) * 96 + qd;
  }

  f32x4 acc[3] = {};

  const float* xa = x + (size_t)(r0 + ml) * EMBED + qd * 8;

  float4 ca0 = *(const float4*)(xa);
  float4 ca1 = *(const float4*)(xa + 4);
  bf16x8 cbh[3], cbl[2];
#pragma unroll
  for (int j = 0; j < 3; ++j) cbh[j] = wt[bh_base[j]];
#pragma unroll
  for (int j = 0; j < 2; ++j) cbl[j] = wt[bl_base[j]];

  for (int ks = 0; ks < 24; ++ks) {
    float4 na0, na1; bf16x8 nbh[3], nbl[2];
    if (ks < 23) {
      const float* p = xa + (ks + 1) * 32;
      na0 = *(const float4*)(p);
      na1 = *(const float4*)(p + 4);
      const int ko = (ks + 1) * 4;
#pragma unroll
      for (int j = 0; j < 3; ++j) nbh[j] = wt[bh_base[j] + ko];
#pragma unroll
      for (int j = 0; j < 2; ++j) nbl[j] = wt[bl_base[j] + ko];
    }

    bf16x8 ah, al;
    split8(ca0, ca1, ah, al);

#pragma unroll
    for (int j = 0; j < 2; ++j) {
      acc[j] = __builtin_amdgcn_mfma_f32_16x16x32_bf16(al, cbh[j], acc[j], 0, 0, 0);
      acc[j] = __builtin_amdgcn_mfma_f32_16x16x32_bf16(ah, cbl[j], acc[j], 0, 0, 0);
      acc[j] = __builtin_amdgcn_mfma_f32_16x16x32_bf16(ah, cbh[j], acc[j], 0, 0, 0);
    }
    acc[2] = __builtin_amdgcn_mfma_f32_16x16x32_bf16(ah, cbh[2], acc[2], 0, 0, 0);

    ca0 = na0; ca1 = na1;
#pragma unroll
    for (int j = 0; j < 3; ++j) cbh[j] = nbh[j];
#pragma unroll
    for (int j = 0; j < 2; ++j) cbl[j] = nbl[j];
  }

  // epilogue. C/D layout: col = lane&15 (n), row = qd*4 + reg (m).
#pragma unroll
  for (int j = 0; j < 3; ++j) {
    const int n = nn[j];
    const float bias = (n < 64) ? bq[n] : (n < 128) ? bk[n - 64] : bv[n - 128];
    float o[4];
#pragma unroll
    for (int reg = 0; reg < 4; ++reg) o[reg] = acc[j][reg] + bias;

    if (j == 2) {                       // V tile: reduce rows -> Vsum
      float ssum = o[0] + o[1] + o[2] + o[3];
      ssum += __shfl_xor(ssum, 16, 64);
      ssum += __shfl_xor(ssum, 32, 64);
      if (qd == 0) atomicAdd(&Vsum[batch * 64 + (n - 128)], ssum);
    }
#pragma unroll
    for (int reg = 0; reg < 4; ++reg) {
      int row = r0 + qd * 4 + reg;
      C[(size_t)row * CN + n] = o[reg];
    }
  }
}

// ---------------------------------------------------------------------------
// Per-row scores + softmax-with-zero-background + V combine (faithful quirk).
// ---------------------------------------------------------------------------
__global__ __launch_bounds__(256) void attn_kernel(const float* __restrict__ C,
                                                   const float* __restrict__ Vsum,
                                                   float* __restrict__ out) {
  const int t    = threadIdx.x;
  const int lane = t & 63;
  const int wave = t >> 6;
  const int r = blockIdx.x * 4 + wave;
  const int b = r >> 12;
  const int i = r & (NTOK - 1);

  const float q  = C[(size_t)r * CN + lane];
  const float kc = C[(size_t)r * CN + 64 + lane];
  float km = 0.f, kp = 0.f;
  if (i > 0)        km = C[(size_t)(r - 1) * CN + 64 + lane];
  if (i < NTOK - 1) kp = C[(size_t)(r + 1) * CN + 64 + lane];

  float p0 = q * km, p1 = q * kc, p2 = q * kp;
#pragma unroll
  for (int off = 32; off > 0; off >>= 1) {
    p0 += __shfl_xor(p0, off, 64);
    p1 += __shfl_xor(p1, off, 64);
    p2 += __shfl_xor(p2, off, 64);
  }

  const float s0 = (i > 0) ? p0 : 0.f;
  const float s1 = p1;
  const float s2 = (i < NTOK - 1) ? p2 : 0.f;
  const float m  = fmaxf(fmaxf(s0, s1), fmaxf(s2, 0.f));
  const float e0 = __expf(s0 - m);
  const float e1 = __expf(s1 - m);
  const float e2 = __expf(s2 - m);
  const float ez = __expf(-m);
  const float Z  = e0 + e1 + e2 + (float)(NTOK - 3) * ez;

  const size_t vb = ((size_t)b * NTOK) * CN + 128;
  const float v0 = C[vb + lane];
  const float v1 = C[vb + CN + lane];
  const float v2 = C[vb + 2 * (size_t)CN + lane];
  const float vs = Vsum[b * 64 + lane];

  out[(size_t)r * 64 + lane] =
      (e0 * v0 + e1 * v1 + e2 * v2 + ez * (vs - v0 - v1 - v2)) / Z;
}

// ---------------------------------------------------------------------------
extern "C" void kernel_launch(void* const* d_in, const int* in_sizes, int n_in,
                              void* d_out, int out_size, void* d_ws, size_t ws_size,
                              hipStream_t stream) {
  const float* x  = (const float*)d_in[0];
  const float* Wq = (const float*)d_in[1];
  const float* bq = (const float*)d_in[2];
  const float* Wk = (const float*)d_in[3];
  const float* bk = (const float*)d_in[4];
  const float* Wv = (const float*)d_in[5];
  const float* bv = (const float*)d_in[6];
  float* out = (float*)d_out;

  float* C    = (float*)d_ws;                       // 16384 x 192 fp32 (12 MiB)
  float* Vsum = C + (size_t)ROWS * CN;              // 4 x 64
  unsigned short* Wt = (unsigned short*)(Vsum + NB * 64);  // 2 x 192 x 768 bf16

  wprep<<<36, 256, 0, stream>>>(Wq, Wk, Wv, Wt, Vsum);
  qkv_mfma<<<1024, 256, 0, stream>>>(x, Wt, bq, bk, bv, C, Vsum);
  attn_kernel<<<ROWS / 4, 256, 0, stream>>>(C, Vsum, out);
}

// Round 6
// 172.336 us; speedup vs baseline: 1.0186x; 1.0186x over previous
//
#include <hip/hip_runtime.h>
#include <hip/hip_bf16.h>
#include <math.h>

#define EMBED 768
#define NTOK  4096
#define NB    4
#define ROWS  16384          // 4 * 4096
#define CN    192            // Q(64)|K(64)|V(64)

typedef __attribute__((ext_vector_type(8))) short bf16x8;       // 8 bf16 = 4 VGPR
typedef __attribute__((ext_vector_type(4))) float f32x4;        // MFMA acc
typedef __attribute__((ext_vector_type(4))) unsigned int u32x4; // 4 dwords

// Split fp32 -> h + l bf16 via packed RNE converts (~3 VALU/elem).
// f = h + l + eps, |eps| ~ 2^-18 |f|  (f - h is exact in fp32).
__device__ inline void split8(const float4& a0, const float4& a1,
                              bf16x8& h, bf16x8& l) {
  const float f[8] = {a0.x, a0.y, a0.z, a0.w, a1.x, a1.y, a1.z, a1.w};
  u32x4 hw, lw;
#pragma unroll
  for (int j = 0; j < 4; ++j) {
    float2 p = make_float2(f[2 * j], f[2 * j + 1]);
    __hip_bfloat162 hb = __float22bfloat162_rn(p);
    float2 hf = __bfloat1622float2(hb);
    __hip_bfloat162 lb =
        __float22bfloat162_rn(make_float2(p.x - hf.x, p.y - hf.y));
    union { __hip_bfloat162 b; unsigned u; } cu, cl;
    cu.b = hb; cl.b = lb;
    hw[j] = cu.u; lw[j] = cl.u;
  }
  h = __builtin_bit_cast(bf16x8, hw);
  l = __builtin_bit_cast(bf16x8, lw);
}

__device__ inline void split1(float f, unsigned short& h, unsigned short& l) {
  __hip_bfloat16 hb = __float2bfloat16(f);
  float hf = __bfloat162float(hb);
  __hip_bfloat16 lb = __float2bfloat16(f - hf);
  union { __hip_bfloat16 b; unsigned short u; } a, b2;
  a.b = hb; b2.b = lb;
  h = a.u; l = b2.u;
}

// ---------------------------------------------------------------------------
// W prep via LDS transpose: Wt[plane][n][k] bf16 (plane 0=high, 1=low).
// Grid 36 blocks: (k-tile 0..11) x (matrix 0..2). Block 0 zeroes Vsum.
// ---------------------------------------------------------------------------
__global__ __launch_bounds__(256) void wprep(const float* __restrict__ Wq,
                                             const float* __restrict__ Wk,
                                             const float* __restrict__ Wv,
                                             unsigned short* __restrict__ Wt,
                                             float* __restrict__ Vsum) {
  __shared__ float ld[64][65];
  const int t   = threadIdx.x;
  const int kt  = blockIdx.x / 3;     // k-tile: rows [kt*64, kt*64+64)
  const int mtx = blockIdx.x % 3;     // 0=Q, 1=K, 2=V
  const float* src = (mtx == 0) ? Wq : (mtx == 1) ? Wk : Wv;

  if (blockIdx.x == 0) Vsum[t] = 0.f;   // NB*64 == 256

  const int col = t & 63;
  const int kr0 = (t >> 6) * 16;
#pragma unroll
  for (int r = 0; r < 16; ++r)
    ld[kr0 + r][col] = src[(size_t)(kt * 64 + kr0 + r) * 64 + col];
  __syncthreads();

  const int nl = t >> 2;
  const int kc = (t & 3) * 16;
  unsigned short hb[16], lb2[16];
#pragma unroll
  for (int r = 0; r < 16; ++r) split1(ld[kc + r][nl], hb[r], lb2[r]);

  const int n = mtx * 64 + nl;
  unsigned short* dh = Wt + (size_t)n * EMBED + kt * 64 + kc;
  unsigned short* dl = Wt + (size_t)(CN + n) * EMBED + kt * 64 + kc;
  *(u32x4*)(dh)     = *(u32x4*)(hb);
  *(u32x4*)(dh + 8) = *(u32x4*)(hb + 8);
  *(u32x4*)(dl)     = *(u32x4*)(lb2);
  *(u32x4*)(dl + 8) = *(u32x4*)(lb2 + 8);
}

// ---------------------------------------------------------------------------
// MFMA GEMM: C[16384][192] = x @ W + bias, split-bf16, flat register pipeline.
// waves_per_eu(4,4): pin exactly 4 waves/EU -> 128-VGPR budget, so the
// scheduler cannot "win" occupancy by shrinking registers and killing the
// 1-deep prefetch (R3-R5 failure mode: VGPR collapsed to 32-44, MfmaUtil ~5%).
// Block = 256 thr = 4 waves, m-tile 16 rows; wave wn covers n-tiles
// {wn, wn+4, wn+8} = 2 Q/K tiles (3-pass) + 1 V tile (1-pass) = 7 MFMA/ks.
// Grid 1024 blocks -> 4096 waves = 4 waves/SIMD. B frags from L2 (Wt 576KB).
// ---------------------------------------------------------------------------
__global__ __launch_bounds__(256)
__attribute__((amdgpu_waves_per_eu(4, 4))) void qkv_mfma(
    const float* __restrict__ x, const unsigned short* __restrict__ Wtu,
    const float* __restrict__ bq, const float* __restrict__ bk,
    const float* __restrict__ bv, float* __restrict__ C,
    float* __restrict__ Vsum) {
  const int lane = threadIdx.x & 63;
  const int wn   = threadIdx.x >> 6;   // 0..3
  const int ml   = lane & 15;
  const int qd   = lane >> 4;          // quad: k = qd*8 + j
  const int r0   = blockIdx.x * 16;
  const int batch = blockIdx.x >> 8;   // 256 blocks per batch

  const bf16x8* wt = (const bf16x8*)Wtu;

  int nn[3], bh_base[3], bl_base[2];
#pragma unroll
  for (int j = 0; j < 3; ++j) {
    nn[j] = (wn + 4 * j) * 16 + ml;
    bh_base[j] = nn[j] * 96 + qd;
    if (j < 2) bl_base[j] = (CN + nn[j]) * 96 + qd;
  }

  f32x4 acc[3] = {};

  const float* xa = x + (size_t)(r0 + ml) * EMBED + qd * 8;

  float4 ca0 = *(const float4*)(xa);
  float4 ca1 = *(const float4*)(xa + 4);
  bf16x8 cbh[3], cbl[2];
#pragma unroll
  for (int j = 0; j < 3; ++j) cbh[j] = wt[bh_base[j]];
#pragma unroll
  for (int j = 0; j < 2; ++j) cbl[j] = wt[bl_base[j]];

  for (int ks = 0; ks < 24; ++ks) {
    float4 na0, na1; bf16x8 nbh[3], nbl[2];
    if (ks < 23) {
      const float* p = xa + (ks + 1) * 32;
      na0 = *(const float4*)(p);
      na1 = *(const float4*)(p + 4);
      const int ko = (ks + 1) * 4;
#pragma unroll
      for (int j = 0; j < 3; ++j) nbh[j] = wt[bh_base[j] + ko];
#pragma unroll
      for (int j = 0; j < 2; ++j) nbl[j] = wt[bl_base[j] + ko];
    }

    bf16x8 ah, al;
    split8(ca0, ca1, ah, al);

#pragma unroll
    for (int j = 0; j < 2; ++j) {
      acc[j] = __builtin_amdgcn_mfma_f32_16x16x32_bf16(al, cbh[j], acc[j], 0, 0, 0);
      acc[j] = __builtin_amdgcn_mfma_f32_16x16x32_bf16(ah, cbl[j], acc[j], 0, 0, 0);
      acc[j] = __builtin_amdgcn_mfma_f32_16x16x32_bf16(ah, cbh[j], acc[j], 0, 0, 0);
    }
    acc[2] = __builtin_amdgcn_mfma_f32_16x16x32_bf16(ah, cbh[2], acc[2], 0, 0, 0);

    ca0 = na0; ca1 = na1;
#pragma unroll
    for (int j = 0; j < 3; ++j) cbh[j] = nbh[j];
#pragma unroll
    for (int j = 0; j < 2; ++j) cbl[j] = nbl[j];
  }

  // epilogue. C/D layout: col = lane&15 (n), row = qd*4 + reg (m).
#pragma unroll
  for (int j = 0; j < 3; ++j) {
    const int n = nn[j];
    const float bias = (n < 64) ? bq[n] : (n < 128) ? bk[n - 64] : bv[n - 128];
    float o[4];
#pragma unroll
    for (int reg = 0; reg < 4; ++reg) o[reg] = acc[j][reg] + bias;

    if (j == 2) {                       // V tile: reduce rows -> Vsum
      float ssum = o[0] + o[1] + o[2] + o[3];
      ssum += __shfl_xor(ssum, 16, 64);
      ssum += __shfl_xor(ssum, 32, 64);
      if (qd == 0) atomicAdd(&Vsum[batch * 64 + (n - 128)], ssum);
    }
#pragma unroll
    for (int reg = 0; reg < 4; ++reg) {
      int row = r0 + qd * 4 + reg;
      C[(size_t)row * CN + n] = o[reg];
    }
  }
}

// ---------------------------------------------------------------------------
// Per-row scores + softmax-with-zero-background + V combine (faithful quirk).
// Vectorized: 4 rows per wave; lane = (row-sub = lane>>4, float4 k-slice).
// All loads/stores 16 B/lane; 12 shfls per wave (butterfly within 16 lanes
// leaves the full sum in every lane of the group).
// ---------------------------------------------------------------------------
__global__ __launch_bounds__(256) void attn_kernel(const float* __restrict__ C,
                                                   const float* __restrict__ Vsum,
                                                   float* __restrict__ out) {
  const int t    = threadIdx.x;
  const int lane = t & 63;
  const int wv   = t >> 6;             // 0..3
  const int rsub = lane >> 4;          // 0..3
  const int d0   = (lane & 15) * 4;
  const int r = blockIdx.x * 16 + wv * 4 + rsub;
  const int b = r >> 12;
  const int i = r & (NTOK - 1);

  const float4 q  = *(const float4*)&C[(size_t)r * CN + d0];
  const float4 kc = *(const float4*)&C[(size_t)r * CN + 64 + d0];
  float4 km = make_float4(0.f, 0.f, 0.f, 0.f);
  float4 kp = make_float4(0.f, 0.f, 0.f, 0.f);
  if (i > 0)        km = *(const float4*)&C[(size_t)(r - 1) * CN + 64 + d0];
  if (i < NTOK - 1) kp = *(const float4*)&C[(size_t)(r + 1) * CN + 64 + d0];

  float p0 = q.x * km.x + q.y * km.y + q.z * km.z + q.w * km.w;
  float p1 = q.x * kc.x + q.y * kc.y + q.z * kc.z + q.w * kc.w;
  float p2 = q.x * kp.x + q.y * kp.y + q.z * kp.z + q.w * kp.w;
#pragma unroll
  for (int off = 8; off > 0; off >>= 1) {
    p0 += __shfl_xor(p0, off, 64);
    p1 += __shfl_xor(p1, off, 64);
    p2 += __shfl_xor(p2, off, 64);
  }

  const float s0 = (i > 0) ? p0 : 0.f;
  const float s1 = p1;
  const float s2 = (i < NTOK - 1) ? p2 : 0.f;
  const float m  = fmaxf(fmaxf(s0, s1), fmaxf(s2, 0.f));
  const float e0 = __expf(s0 - m);
  const float e1 = __expf(s1 - m);
  const float e2 = __expf(s2 - m);
  const float ez = __expf(-m);
  const float Z  = e0 + e1 + e2 + (float)(NTOK - 3) * ez;

  const size_t vb = ((size_t)b * NTOK) * CN + 128;
  const float4 v0 = *(const float4*)&C[vb + d0];
  const float4 v1 = *(const float4*)&C[vb + CN + d0];
  const float4 v2 = *(const float4*)&C[vb + 2 * (size_t)CN + d0];
  const float4 vs = *(const float4*)&Vsum[b * 64 + d0];

  float4 o;
  o.x = (e0 * v0.x + e1 * v1.x + e2 * v2.x + ez * (vs.x - v0.x - v1.x - v2.x)) / Z;
  o.y = (e0 * v0.y + e1 * v1.y + e2 * v2.y + ez * (vs.y - v0.y - v1.y - v2.y)) / Z;
  o.z = (e0 * v0.z + e1 * v1.z + e2 * v2.z + ez * (vs.z - v0.z - v1.z - v2.z)) / Z;
  o.w = (e0 * v0.w + e1 * v1.w + e2 * v2.w + ez * (vs.w - v0.w - v1.w - v2.w)) / Z;
  *(float4*)&out[(size_t)r * 64 + d0] = o;
}

// ---------------------------------------------------------------------------
extern "C" void kernel_launch(void* const* d_in, const int* in_sizes, int n_in,
                              void* d_out, int out_size, void* d_ws, size_t ws_size,
                              hipStream_t stream) {
  const float* x  = (const float*)d_in[0];
  const float* Wq = (const float*)d_in[1];
  const float* bq = (const float*)d_in[2];
  const float* Wk = (const float*)d_in[3];
  const float* bk = (const float*)d_in[4];
  const float* Wv = (const float*)d_in[5];
  const float* bv = (const float*)d_in[6];
  float* out = (float*)d_out;

  float* C    = (float*)d_ws;                       // 16384 x 192 fp32 (12 MiB)
  float* Vsum = C + (size_t)ROWS * CN;              // 4 x 64
  unsigned short* Wt = (unsigned short*)(Vsum + NB * 64);  // 2 x 192 x 768 bf16

  wprep<<<36, 256, 0, stream>>>(Wq, Wk, Wv, Wt, Vsum);
  qkv_mfma<<<1024, 256, 0, stream>>>(x, Wt, bq, bk, bv, C, Vsum);
  attn_kernel<<<ROWS / 16, 256, 0, stream>>>(C, Vsum, out);
}